// Round 1
// baseline (634.283 us; speedup 1.0000x reference)
//
#include <hip/hip_runtime.h>

// GCN policy net: 2× GCNConv(H=16) + global max pool + linear head.
// Strategy: build CSR (by dst) once per call, then both conv layers are pure
// gather (no float atomics). g[n][c] = dis[n]*(h@W)[n][c]; aggregation:
// h_out[n] = relu(dis[n]*(g[n] + sum_{src in in(n)} g[src]) + b).

#define FIN 128
#define HDIM 16
#define AOUT 10

__global__ void k_count(const int* __restrict__ dst, int E, int* __restrict__ cnt) {
    int e = blockIdx.x * blockDim.x + threadIdx.x;
    if (e < E) atomicAdd(&cnt[dst[e]], 1);
}

// exclusive scan, stage 1: 1024 elements per block (256 thr x 4)
__global__ __launch_bounds__(256) void k_scan1(const int* __restrict__ cnt, int n,
                                               int* __restrict__ off, int* __restrict__ bsum) {
    __shared__ int s[256];
    int t = threadIdx.x;
    int base = blockIdx.x * 1024 + t * 4;
    int v[4];
#pragma unroll
    for (int j = 0; j < 4; j++) v[j] = (base + j < n) ? cnt[base + j] : 0;
    int tsum = v[0] + v[1] + v[2] + v[3];
    s[t] = tsum;
    for (int d = 1; d < 256; d <<= 1) {
        __syncthreads();
        int add = (t >= d) ? s[t - d] : 0;
        __syncthreads();
        s[t] += add;
    }
    __syncthreads();
    int incl = s[t];
    int run = incl - tsum;  // exclusive base for this thread
#pragma unroll
    for (int j = 0; j < 4; j++) {
        if (base + j < n) off[base + j] = run;
        run += v[j];
    }
    if (t == 255) bsum[blockIdx.x] = incl;
}

// stage 2: exclusive scan of block sums (nb <= 1024), single block
__global__ void k_scan2(int* __restrict__ bsum, int nb) {
    __shared__ int s[1024];
    int t = threadIdx.x;
    for (int i = t; i < nb; i += blockDim.x) s[i] = bsum[i];
    __syncthreads();
    if (t == 0) {
        int run = 0;
        for (int i = 0; i < nb; i++) { int v = s[i]; s[i] = run; run += v; }
    }
    __syncthreads();
    for (int i = t; i < nb; i += blockDim.x) bsum[i] = s[i];
}

// stage 3: finalize offsets, init cursor, compute dis = 1/sqrt(deg_in + 1)
__global__ void k_scan3(int* __restrict__ off, const int* __restrict__ bsum,
                        int* __restrict__ cursor, const int* __restrict__ cnt,
                        float* __restrict__ dis, int n) {
    int i = blockIdx.x * blockDim.x + threadIdx.x;
    if (i < n) {
        int o = off[i] + bsum[i >> 10];
        off[i] = o;
        cursor[i] = o;
        dis[i] = 1.0f / sqrtf((float)(cnt[i] + 1));
    }
}

__global__ void k_scatter(const int* __restrict__ src, const int* __restrict__ dst, int E,
                          int* __restrict__ cursor, int* __restrict__ srcidx) {
    int e = blockIdx.x * blockDim.x + threadIdx.x;
    if (e < E) {
        int d = dst[e];
        int pos = atomicAdd(&cursor[d], 1);
        srcidx[pos] = src[e];
    }
}

// g[n][c] = dis[n] * sum_k x[n][k] * W1[k][c]      (x: [n,128], W1: [128,16])
__global__ __launch_bounds__(256) void k_gemm1(const float* __restrict__ x,
                                               const float* __restrict__ W1,
                                               const float* __restrict__ dis,
                                               float* __restrict__ g, int n) {
    __shared__ float Ws[FIN * HDIM];
    for (int i = threadIdx.x; i < FIN * HDIM; i += 256) Ws[i] = W1[i];
    __syncthreads();
    int t = threadIdx.x;
    int node = blockIdx.x * 16 + (t >> 4);
    int c = t & 15;
    if (node >= n) return;
    const float* xr = x + (size_t)node * FIN;
    float acc = 0.f;
#pragma unroll
    for (int k = 0; k < FIN; k += 4) {
        float4 xv = *reinterpret_cast<const float4*>(xr + k);
        acc += xv.x * Ws[(k + 0) * HDIM + c];
        acc += xv.y * Ws[(k + 1) * HDIM + c];
        acc += xv.z * Ws[(k + 2) * HDIM + c];
        acc += xv.w * Ws[(k + 3) * HDIM + c];
    }
    g[(size_t)node * HDIM + c] = dis[node] * acc;
}

// aggregation: one wave per node; lane = q*16 + c, q in 0..3 strides edges.
// h[n][c] = relu(dis[n] * (g[n][c] + sum_edges g[src][c]) + b[c])
__global__ __launch_bounds__(256) void k_agg(const float* __restrict__ g,
                                             const int* __restrict__ off,
                                             const int* __restrict__ srcidx,
                                             const float* __restrict__ dis,
                                             const float* __restrict__ b,
                                             float* __restrict__ h, int n, int E) {
    int t = threadIdx.x;
    int lane = t & 63;
    int c = lane & 15;
    int q = lane >> 4;                    // 0..3
    int node = blockIdx.x * 4 + (t >> 6); // one node per wave
    if (node >= n) return;
    int e0 = off[node];
    int e1 = (node + 1 < n) ? off[node + 1] : E;
    float acc = (q == 0) ? g[(size_t)node * HDIM + c] : 0.f;  // self-loop term
    for (int e = e0 + q; e < e1; e += 4) {
        int s = srcidx[e];
        acc += g[(size_t)s * HDIM + c];
    }
    acc += __shfl_xor(acc, 16);
    acc += __shfl_xor(acc, 32);
    if (q == 0) {
        float v = dis[node] * acc + b[c];
        h[(size_t)node * HDIM + c] = fmaxf(v, 0.f);
    }
}

// g2[n][c] = dis[n] * sum_j h[n][j] * W2[j][c]   (W2: [16,16])
__global__ __launch_bounds__(256) void k_gemm2(const float* __restrict__ h,
                                               const float* __restrict__ W2,
                                               const float* __restrict__ dis,
                                               float* __restrict__ g, int n) {
    __shared__ float Ws[HDIM * HDIM];
    if (threadIdx.x < HDIM * HDIM) Ws[threadIdx.x] = W2[threadIdx.x];
    __syncthreads();
    int t = threadIdx.x;
    int node = blockIdx.x * 16 + (t >> 4);
    int c = t & 15;
    if (node >= n) return;
    const float* hr = h + (size_t)node * HDIM;
    float acc = 0.f;
#pragma unroll
    for (int j = 0; j < HDIM; j++) acc += hr[j] * Ws[j * HDIM + c];
    g[(size_t)node * HDIM + c] = dis[node] * acc;
}

// global max pool over nodes (h >= 0 after relu, so uint atomicMax works)
__global__ __launch_bounds__(256) void k_maxpool(const float* __restrict__ h,
                                                 unsigned int* __restrict__ pooled, int n) {
    int t = threadIdx.x;
    int c = t & 15;
    int grp = t >> 4;  // 16 groups per block
    float m = 0.f;
    for (int node = blockIdx.x * 16 + grp; node < n; node += gridDim.x * 16)
        m = fmaxf(m, h[(size_t)node * HDIM + c]);
    __shared__ float s[256];
    s[t] = m;
    __syncthreads();
    for (int d = 128; d >= 16; d >>= 1) {
        if (t < d) s[t] = fmaxf(s[t], s[t + d]);
        __syncthreads();
    }
    if (t < 16) atomicMax(&pooled[t], __float_as_uint(s[t]));
}

// out[a] = sum_c pooled[c] * Wc[c][a] + bc[a]   (Wc: [16,10])
__global__ void k_final(const unsigned int* __restrict__ pooled, const float* __restrict__ Wc,
                        const float* __restrict__ bc, float* __restrict__ out) {
    __shared__ float p[HDIM];
    int t = threadIdx.x;
    if (t < HDIM) p[t] = __uint_as_float(pooled[t]);
    __syncthreads();
    if (t < AOUT) {
        float acc = bc[t];
#pragma unroll
        for (int c = 0; c < HDIM; c++) acc += p[c] * Wc[c * AOUT + t];
        out[t] = acc;
    }
}

extern "C" void kernel_launch(void* const* d_in, const int* in_sizes, int n_in,
                              void* d_out, int out_size, void* d_ws, size_t ws_size,
                              hipStream_t stream) {
    const float* x  = (const float*)d_in[0];
    const int*   ei = (const int*)d_in[1];
    const float* W1 = (const float*)d_in[2];
    const float* b1 = (const float*)d_in[3];
    const float* W2 = (const float*)d_in[4];
    const float* b2 = (const float*)d_in[5];
    const float* Wc = (const float*)d_in[6];
    const float* bc = (const float*)d_in[7];
    float* out = (float*)d_out;

    int n = in_sizes[0] / FIN;
    int E = in_sizes[1] / 2;
    const int* srcp = ei;       // edge_index[0]
    const int* dstp = ei + E;   // edge_index[1]

    char* ws = (char*)d_ws;
    auto alloc = [&](size_t bytes) -> char* {
        char* p = ws;
        ws += (bytes + 255) & ~(size_t)255;
        return p;
    };
    float* dis    = (float*)alloc((size_t)n * 4);
    int*   cnt    = (int*)alloc((size_t)n * 4);
    int*   off    = (int*)alloc((size_t)n * 4);
    int*   cursor = (int*)alloc((size_t)n * 4);
    int*   bsum   = (int*)alloc(4096);
    int*   srcidx = (int*)alloc((size_t)E * 4);
    float* g      = (float*)alloc((size_t)n * HDIM * 4);
    float* h      = (float*)alloc((size_t)n * HDIM * 4);
    unsigned int* pooled = (unsigned int*)alloc(64);

    hipMemsetAsync(cnt, 0, (size_t)n * 4, stream);
    hipMemsetAsync(pooled, 0, 64, stream);

    k_count<<<(E + 255) / 256, 256, 0, stream>>>(dstp, E, cnt);
    int nb = (n + 1023) / 1024;
    k_scan1<<<nb, 256, 0, stream>>>(cnt, n, off, bsum);
    k_scan2<<<1, 256, 0, stream>>>(bsum, nb);
    k_scan3<<<(n + 255) / 256, 256, 0, stream>>>(off, bsum, cursor, cnt, dis, n);
    k_scatter<<<(E + 255) / 256, 256, 0, stream>>>(srcp, dstp, E, cursor, srcidx);

    k_gemm1<<<(n + 15) / 16, 256, 0, stream>>>(x, W1, dis, g, n);
    k_agg<<<(n + 3) / 4, 256, 0, stream>>>(g, off, srcidx, dis, b1, h, n, E);
    k_gemm2<<<(n + 15) / 16, 256, 0, stream>>>(h, W2, dis, g, n);
    k_agg<<<(n + 3) / 4, 256, 0, stream>>>(g, off, srcidx, dis, b2, h, n, E);

    k_maxpool<<<256, 256, 0, stream>>>(h, pooled, n);
    k_final<<<1, 64, 0, stream>>>(pooled, Wc, bc, out);
}

// Round 2
// 510.919 us; speedup vs baseline: 1.2415x; 1.2415x over previous
//
#include <hip/hip_runtime.h>

// GCN policy net: 2× GCNConv(H=16) + global max pool + linear head.
// CSR build is XCD-range-partitioned: dst space split into 8 contiguous
// ranges, range = blockIdx.x & 7 (matches bid%8 -> XCD round-robin), so each
// XCD's L2 owns one contiguous CSR output chunk -> full-line writebacks
// instead of 16x write amplification.

#define FIN 128
#define HDIM 16
#define AOUT 10
#define NR 8          // dst ranges == XCDs
#define NBLK 2048     // total blocks for count/scatter (256 per range)

__global__ __launch_bounds__(256) void k_count(const int* __restrict__ dst, int E,
                                               int* __restrict__ cnt, int chunk, int n) {
    int range = blockIdx.x & (NR - 1);
    int lo = range * chunk;
    int hi = min(n, lo + chunk);
    int t0 = (blockIdx.x >> 3) * blockDim.x + threadIdx.x;
    int stride = (gridDim.x >> 3) * blockDim.x;
    for (int e = t0; e < E; e += stride) {
        int d = dst[e];
        if (d >= lo && d < hi) atomicAdd(&cnt[d], 1);
    }
}

// exclusive scan, stage 1: 1024 elements per block (256 thr x 4)
__global__ __launch_bounds__(256) void k_scan1(const int* __restrict__ cnt, int n,
                                               int* __restrict__ off, int* __restrict__ bsum) {
    __shared__ int s[256];
    int t = threadIdx.x;
    int base = blockIdx.x * 1024 + t * 4;
    int v[4];
#pragma unroll
    for (int j = 0; j < 4; j++) v[j] = (base + j < n) ? cnt[base + j] : 0;
    int tsum = v[0] + v[1] + v[2] + v[3];
    s[t] = tsum;
    for (int d = 1; d < 256; d <<= 1) {
        __syncthreads();
        int add = (t >= d) ? s[t - d] : 0;
        __syncthreads();
        s[t] += add;
    }
    __syncthreads();
    int incl = s[t];
    int run = incl - tsum;  // exclusive base for this thread
#pragma unroll
    for (int j = 0; j < 4; j++) {
        if (base + j < n) off[base + j] = run;
        run += v[j];
    }
    if (t == 255) bsum[blockIdx.x] = incl;
}

// stage 2: exclusive scan of block sums (nb <= 1024), single block
__global__ void k_scan2(int* __restrict__ bsum, int nb) {
    __shared__ int s[1024];
    int t = threadIdx.x;
    for (int i = t; i < nb; i += blockDim.x) s[i] = bsum[i];
    __syncthreads();
    if (t == 0) {
        int run = 0;
        for (int i = 0; i < nb; i++) { int v = s[i]; s[i] = run; run += v; }
    }
    __syncthreads();
    for (int i = t; i < nb; i += blockDim.x) bsum[i] = s[i];
}

// stage 3: finalize offsets, init cursor, compute dis = 1/sqrt(deg_in + 1)
__global__ void k_scan3(int* __restrict__ off, const int* __restrict__ bsum,
                        int* __restrict__ cursor, const int* __restrict__ cnt,
                        float* __restrict__ dis, int n) {
    int i = blockIdx.x * blockDim.x + threadIdx.x;
    if (i < n) {
        int o = off[i] + bsum[i >> 10];
        off[i] = o;
        cursor[i] = o;
        dis[i] = 1.0f / sqrtf((float)(cnt[i] + 1));
    }
}

__global__ __launch_bounds__(256) void k_scatter(const int* __restrict__ src,
                                                 const int* __restrict__ dst, int E,
                                                 int* __restrict__ cursor,
                                                 int* __restrict__ srcidx,
                                                 int chunk, int n) {
    int range = blockIdx.x & (NR - 1);
    int lo = range * chunk;
    int hi = min(n, lo + chunk);
    int t0 = (blockIdx.x >> 3) * blockDim.x + threadIdx.x;
    int stride = (gridDim.x >> 3) * blockDim.x;
    for (int e = t0; e < E; e += stride) {
        int d = dst[e];
        if (d >= lo && d < hi) {
            int pos = atomicAdd(&cursor[d], 1);
            srcidx[pos] = src[e];
        }
    }
}

// g[n][c] = dis[n] * sum_k x[n][k] * W1[k][c]      (x: [n,128], W1: [128,16])
__global__ __launch_bounds__(256) void k_gemm1(const float* __restrict__ x,
                                               const float* __restrict__ W1,
                                               const float* __restrict__ dis,
                                               float* __restrict__ g, int n) {
    __shared__ float Ws[FIN * HDIM];
    for (int i = threadIdx.x; i < FIN * HDIM; i += 256) Ws[i] = W1[i];
    __syncthreads();
    int t = threadIdx.x;
    int node = blockIdx.x * 16 + (t >> 4);
    int c = t & 15;
    if (node >= n) return;
    const float* xr = x + (size_t)node * FIN;
    float acc = 0.f;
#pragma unroll
    for (int k = 0; k < FIN; k += 4) {
        float4 xv = *reinterpret_cast<const float4*>(xr + k);
        acc += xv.x * Ws[(k + 0) * HDIM + c];
        acc += xv.y * Ws[(k + 1) * HDIM + c];
        acc += xv.z * Ws[(k + 2) * HDIM + c];
        acc += xv.w * Ws[(k + 3) * HDIM + c];
    }
    g[(size_t)node * HDIM + c] = dis[node] * acc;
}

// aggregation: one wave per node; lane = q*16 + c, q in 0..3 strides edges.
// h[n][c] = relu(dis[n] * (g[n][c] + sum_edges g[src][c]) + b[c])
__global__ __launch_bounds__(256) void k_agg(const float* __restrict__ g,
                                             const int* __restrict__ off,
                                             const int* __restrict__ srcidx,
                                             const float* __restrict__ dis,
                                             const float* __restrict__ b,
                                             float* __restrict__ h, int n, int E) {
    int t = threadIdx.x;
    int lane = t & 63;
    int c = lane & 15;
    int q = lane >> 4;                    // 0..3
    int node = blockIdx.x * 4 + (t >> 6); // one node per wave
    if (node >= n) return;
    int e0 = off[node];
    int e1 = (node + 1 < n) ? off[node + 1] : E;
    float acc = (q == 0) ? g[(size_t)node * HDIM + c] : 0.f;  // self-loop term
    for (int e = e0 + q; e < e1; e += 4) {
        int s = srcidx[e];
        acc += g[(size_t)s * HDIM + c];
    }
    acc += __shfl_xor(acc, 16);
    acc += __shfl_xor(acc, 32);
    if (q == 0) {
        float v = dis[node] * acc + b[c];
        h[(size_t)node * HDIM + c] = fmaxf(v, 0.f);
    }
}

// g2[n][c] = dis[n] * sum_j h[n][j] * W2[j][c]   (W2: [16,16])
__global__ __launch_bounds__(256) void k_gemm2(const float* __restrict__ h,
                                               const float* __restrict__ W2,
                                               const float* __restrict__ dis,
                                               float* __restrict__ g, int n) {
    __shared__ float Ws[HDIM * HDIM];
    if (threadIdx.x < HDIM * HDIM) Ws[threadIdx.x] = W2[threadIdx.x];
    __syncthreads();
    int t = threadIdx.x;
    int node = blockIdx.x * 16 + (t >> 4);
    int c = t & 15;
    if (node >= n) return;
    const float* hr = h + (size_t)node * HDIM;
    float acc = 0.f;
#pragma unroll
    for (int j = 0; j < HDIM; j++) acc += hr[j] * Ws[j * HDIM + c];
    g[(size_t)node * HDIM + c] = dis[node] * acc;
}

// global max pool over nodes (h >= 0 after relu, so uint atomicMax works)
__global__ __launch_bounds__(256) void k_maxpool(const float* __restrict__ h,
                                                 unsigned int* __restrict__ pooled, int n) {
    int t = threadIdx.x;
    int c = t & 15;
    int grp = t >> 4;  // 16 groups per block
    float m = 0.f;
    for (int node = blockIdx.x * 16 + grp; node < n; node += gridDim.x * 16)
        m = fmaxf(m, h[(size_t)node * HDIM + c]);
    __shared__ float s[256];
    s[t] = m;
    __syncthreads();
    for (int d = 128; d >= 16; d >>= 1) {
        if (t < d) s[t] = fmaxf(s[t], s[t + d]);
        __syncthreads();
    }
    if (t < 16) atomicMax(&pooled[t], __float_as_uint(s[t]));
}

// out[a] = sum_c pooled[c] * Wc[c][a] + bc[a]   (Wc: [16,10])
__global__ void k_final(const unsigned int* __restrict__ pooled, const float* __restrict__ Wc,
                        const float* __restrict__ bc, float* __restrict__ out) {
    __shared__ float p[HDIM];
    int t = threadIdx.x;
    if (t < HDIM) p[t] = __uint_as_float(pooled[t]);
    __syncthreads();
    if (t < AOUT) {
        float acc = bc[t];
#pragma unroll
        for (int c = 0; c < HDIM; c++) acc += p[c] * Wc[c * AOUT + t];
        out[t] = acc;
    }
}

extern "C" void kernel_launch(void* const* d_in, const int* in_sizes, int n_in,
                              void* d_out, int out_size, void* d_ws, size_t ws_size,
                              hipStream_t stream) {
    const float* x  = (const float*)d_in[0];
    const int*   ei = (const int*)d_in[1];
    const float* W1 = (const float*)d_in[2];
    const float* b1 = (const float*)d_in[3];
    const float* W2 = (const float*)d_in[4];
    const float* b2 = (const float*)d_in[5];
    const float* Wc = (const float*)d_in[6];
    const float* bc = (const float*)d_in[7];
    float* out = (float*)d_out;

    int n = in_sizes[0] / FIN;
    int E = in_sizes[1] / 2;
    const int* srcp = ei;       // edge_index[0]
    const int* dstp = ei + E;   // edge_index[1]
    int chunk = (n + NR - 1) / NR;

    char* ws = (char*)d_ws;
    auto alloc = [&](size_t bytes) -> char* {
        char* p = ws;
        ws += (bytes + 255) & ~(size_t)255;
        return p;
    };
    float* dis    = (float*)alloc((size_t)n * 4);
    int*   cnt    = (int*)alloc((size_t)n * 4);
    int*   off    = (int*)alloc((size_t)n * 4);
    int*   cursor = (int*)alloc((size_t)n * 4);
    int*   bsum   = (int*)alloc(4096);
    int*   srcidx = (int*)alloc((size_t)E * 4);
    float* g      = (float*)alloc((size_t)n * HDIM * 4);
    float* h      = (float*)alloc((size_t)n * HDIM * 4);
    unsigned int* pooled = (unsigned int*)alloc(64);

    hipMemsetAsync(cnt, 0, (size_t)n * 4, stream);
    hipMemsetAsync(pooled, 0, 64, stream);

    k_count<<<NBLK, 256, 0, stream>>>(dstp, E, cnt, chunk, n);
    int nb = (n + 1023) / 1024;
    k_scan1<<<nb, 256, 0, stream>>>(cnt, n, off, bsum);
    k_scan2<<<1, 256, 0, stream>>>(bsum, nb);
    k_scan3<<<(n + 255) / 256, 256, 0, stream>>>(off, bsum, cursor, cnt, dis, n);
    k_scatter<<<NBLK, 256, 0, stream>>>(srcp, dstp, E, cursor, srcidx, chunk, n);

    k_gemm1<<<(n + 15) / 16, 256, 0, stream>>>(x, W1, dis, g, n);
    k_agg<<<(n + 3) / 4, 256, 0, stream>>>(g, off, srcidx, dis, b1, h, n, E);
    k_gemm2<<<(n + 15) / 16, 256, 0, stream>>>(h, W2, dis, g, n);
    k_agg<<<(n + 3) / 4, 256, 0, stream>>>(g, off, srcidx, dis, b2, h, n, E);

    k_maxpool<<<256, 256, 0, stream>>>(h, pooled, n);
    k_final<<<1, 64, 0, stream>>>(pooled, Wc, bc, out);
}